// Round 1
// baseline (7957.589 us; speedup 1.0000x reference)
//
#include <hip/hip_runtime.h>
#include <float.h>

#define BB 128
#define N1 21
#define N2 4096
#define CC 256   // C (points2 channels)
#define LCH 256  // LC
#define HH 128   // H
#define KNN 64
#define CIN 387  // C + H + 3
#define LDSS 257 // padded LDS row stride

// ---- workspace layout (in float units) ----
// p1:   [B*N1][128]
// knn:  [B*N1][64]  (int)
// W1T:  [387][256]
// W2T/W3T/W4T/W5T: [256][256] each
static const size_t OFF_P1  = 0;
static const size_t OFF_KNN = OFF_P1  + (size_t)BB * N1 * HH;     // 344064
static const size_t OFF_W1T = OFF_KNN + (size_t)BB * N1 * KNN;    // +172032
static const size_t OFF_W2T = OFF_W1T + (size_t)CIN * 256;        // +99072
static const size_t OFF_W3T = OFF_W2T + (size_t)256 * 256;
static const size_t OFF_W4T = OFF_W3T + (size_t)256 * 256;
static const size_t OFF_W5T = OFF_W4T + (size_t)256 * 256;

__device__ __forceinline__ float lrelu(float x) { return x > 0.f ? x : 0.1f * x; }

// ---------------- kernel 0: weight transposes ----------------
__global__ __launch_bounds__(256) void k_transpose(
    const float* __restrict__ w1, const float* __restrict__ w2,
    const float* __restrict__ w3, const float* __restrict__ w4,
    const float* __restrict__ w5, float* __restrict__ ws) {
  int t = blockIdx.x * 256 + threadIdx.x;
  float* W1T = ws + OFF_W1T;
  if (t < CIN * 256) {
    int c = t >> 8, o = t & 255;
    W1T[t] = w1[o * CIN + c];
    return;
  }
  int u = t - CIN * 256;
  if (u < 4 * 65536) {
    int m = u >> 16;     // which square matrix
    int v = u & 65535;
    int c = v >> 8, o = v & 255;
    const float* src = (m == 0) ? w2 : (m == 1) ? w3 : (m == 2) ? w4 : w5;
    float* dst = ws + ((m == 0) ? OFF_W2T : (m == 1) ? OFF_W3T : (m == 2) ? OFF_W4T : OFF_W5T);
    dst[v] = src[o * 256 + c];
  }
}

// ---------------- kernel 1: biasfold -> p1 ----------------
__global__ __launch_bounds__(128) void k_biasfold(
    const float* __restrict__ points1,
    const float* __restrict__ w1, const float* __restrict__ bb1,
    const float* __restrict__ g1, const float* __restrict__ be1,
    const float* __restrict__ w2, const float* __restrict__ bb2,
    const float* __restrict__ g2, const float* __restrict__ be2,
    const float* __restrict__ w3, const float* __restrict__ bb3,
    const float* __restrict__ g3, const float* __restrict__ be3,
    float* __restrict__ p1out) {
  int blk = blockIdx.x;
  int b = blk / N1, n = blk % N1;
  int t = threadIdx.x;
  __shared__ float x0[LCH], x1s[HH], x2s[HH];
  const float bnS = 1.0f / sqrtf(1.0f + 1e-5f);

  x0[t]        = points1[((size_t)b * LCH + t) * N1 + n];
  x0[t + 128]  = points1[((size_t)b * LCH + t + 128) * N1 + n];
  __syncthreads();

  // layer 1: 256 -> 128
  {
    float acc = 0.f;
    const float* wr = w1 + (size_t)t * LCH;
    #pragma unroll 4
    for (int c = 0; c < LCH; c++) acc += wr[c] * x0[c];
    acc += bb1[t * N1 + n];
    acc = acc * (g1[t] * bnS) + be1[t];
    x1s[t] = lrelu(acc);
  }
  __syncthreads();
  // layer 2: 128 -> 128
  {
    float acc = 0.f;
    const float* wr = w2 + (size_t)t * HH;
    #pragma unroll 4
    for (int c = 0; c < HH; c++) acc += wr[c] * x1s[c];
    acc += bb2[t * N1 + n];
    acc = acc * (g2[t] * bnS) + be2[t];
    x2s[t] = lrelu(acc);
  }
  __syncthreads();
  // layer 3: 128 -> 128
  {
    float acc = 0.f;
    const float* wr = w3 + (size_t)t * HH;
    #pragma unroll 4
    for (int c = 0; c < HH; c++) acc += wr[c] * x2s[c];
    acc += bb3[t * N1 + n];
    acc = acc * (g3[t] * bnS) + be3[t];
    p1out[(size_t)blk * HH + t] = lrelu(acc);
  }
}

// ---------------- kernel 2: kNN (64 smallest of 4096) ----------------
__global__ __launch_bounds__(256) void k_knn(
    const float* __restrict__ xyz1, const float* __restrict__ xyz2,
    int* __restrict__ knn) {
  int blk = blockIdx.x;
  int b = blk / N1, n = blk % N1;
  int t = threadIdx.x;
  __shared__ float dist[N2];
  __shared__ float wvv[4];
  __shared__ int wii[4];

  float ax = xyz1[((size_t)b * 3 + 0) * N1 + n];
  float ay = xyz1[((size_t)b * 3 + 1) * N1 + n];
  float az = xyz1[((size_t)b * 3 + 2) * N1 + n];
  float xx1 = ax * ax + ay * ay + az * az;
  const float* X = xyz2 + (size_t)b * 3 * N2;

  for (int i = 0; i < 16; i++) {
    int j = t + i * 256;
    float px = X[j], py = X[N2 + j], pz = X[2 * N2 + j];
    float xx2 = px * px + py * py + pz * pz;
    float dot = ax * px + ay * py + az * pz;
    dist[j] = (xx1 + xx2) - 2.0f * dot;
  }
  __syncthreads();

  int* out = knn + (size_t)blk * KNN;
  for (int it = 0; it < KNN; it++) {
    float best = FLT_MAX;
    int bi = N2;
    for (int i = 0; i < 16; i++) {
      int j = t + i * 256;
      float v = dist[j];
      if (v < best) { best = v; bi = j; }   // strict <: keeps lowest index in-thread
    }
    for (int off = 32; off; off >>= 1) {
      float ov = __shfl_down(best, off);
      int oi = __shfl_down(bi, off);
      if (ov < best || (ov == best && oi < bi)) { best = ov; bi = oi; }
    }
    int w = t >> 6;
    if ((t & 63) == 0) { wvv[w] = best; wii[w] = bi; }
    __syncthreads();
    if (t == 0) {
      float bv = wvv[0]; int bj = wii[0];
      for (int q = 1; q < 4; q++)
        if (wvv[q] < bv || (wvv[q] == bv && wii[q] < bj)) { bv = wvv[q]; bj = wii[q]; }
      out[it] = bj;
      dist[bj] = FLT_MAX;
    }
    __syncthreads();
  }
}

// one 256->256 MLP layer on a [16][256] tile; thread (kk,og) computes 16 outputs
__device__ __forceinline__ void mlp_layer256(
    const float* __restrict__ xin,    // LDS [16][LDSS]
    const float* __restrict__ WT,     // global [256][256] transposed
    const float* __restrict__ bias,   // [256]
    float* __restrict__ yout,         // LDS [16][LDSS]
    int kk, int og) {
  float acc[16];
  #pragma unroll
  for (int j = 0; j < 16; j++) acc[j] = 0.f;
  const float* xrow = xin + kk * LDSS;
  for (int c = 0; c < 256; c++) {
    float xv = xrow[c];
    const float* wp = WT + (size_t)c * 256 + og * 16;
    #pragma unroll
    for (int j4 = 0; j4 < 4; j4++) {
      float4 w4 = *(const float4*)(wp + j4 * 4);
      acc[j4 * 4 + 0] = fmaf(w4.x, xv, acc[j4 * 4 + 0]);
      acc[j4 * 4 + 1] = fmaf(w4.y, xv, acc[j4 * 4 + 1]);
      acc[j4 * 4 + 2] = fmaf(w4.z, xv, acc[j4 * 4 + 2]);
      acc[j4 * 4 + 3] = fmaf(w4.w, xv, acc[j4 * 4 + 3]);
    }
  }
  #pragma unroll
  for (int j = 0; j < 16; j++) {
    int o = og * 16 + j;
    yout[kk * LDSS + o] = lrelu(acc[j] + bias[o]);
  }
}

// ---------------- kernel 3: fused gather + MLP + maxpool + mlp2 + regress ----------------
__global__ __launch_bounds__(256) void k_fused(
    const float* __restrict__ xyz1, const float* __restrict__ xyz2,
    const float* __restrict__ points2,
    const float* __restrict__ p1ws, const int* __restrict__ knn,
    const float* __restrict__ W1T, const float* __restrict__ b1,
    const float* __restrict__ W2T, const float* __restrict__ b2,
    const float* __restrict__ W3T, const float* __restrict__ b3,
    const float* __restrict__ W4T, const float* __restrict__ W5T,
    const float* __restrict__ regw, const float* __restrict__ regb,
    float* __restrict__ out) {
  int blk = blockIdx.x;
  int b = blk / N1, n = blk % N1;
  int t = threadIdx.x;

  __shared__ float g2t[16 * LDSS], y1[16 * LDSS], y2[16 * LDSS];
  __shared__ float A1[256], pooled[256], z1[256], z2[256];
  __shared__ float p1row[HH];
  __shared__ float dirs[16][4];
  __shared__ int idxs[KNN];
  __shared__ float x1p[3];

  if (t < KNN) idxs[t] = knn[(size_t)blk * KNN + t];
  if (t < HH) p1row[t] = p1ws[(size_t)blk * HH + t];
  if (t < 3) x1p[t] = xyz1[((size_t)b * 3 + t) * N1 + n];
  pooled[t] = -FLT_MAX;
  __syncthreads();

  // A1[o] = sum_{c<128} W1[o][c] * p1[c]   (g1 part, k-independent)
  {
    float acc = 0.f;
    for (int c = 0; c < HH; c++) acc += W1T[(size_t)c * 256 + t] * p1row[c];
    A1[t] = acc;
  }
  __syncthreads();

  const float* p2b = points2 + (size_t)b * CC * N2;
  const float* x2b = xyz2 + (size_t)b * 3 * N2;
  int kk = t >> 4, og = t & 15;

  for (int tile = 0; tile < 4; tile++) {
    int kb = tile * 16;
    // gather g2 tile [16 k][256 c]
    {
      int k = t & 15, c0 = t >> 4;
      int id = idxs[kb + k];
      for (int i = 0; i < 16; i++) {
        int c = c0 + i * 16;
        g2t[k * LDSS + c] = p2b[(size_t)c * N2 + id];
      }
    }
    if (t < 48) {
      int k = t / 3, d = t - 3 * k;
      dirs[k][d] = x2b[(size_t)d * N2 + idxs[kb + k]] - x1p[d];
    }
    __syncthreads();

    // layer 1: 387 -> 256
    {
      float acc[16];
      #pragma unroll
      for (int j = 0; j < 16; j++) acc[j] = A1[og * 16 + j];
      const float* xrow = g2t + kk * LDSS;
      for (int c = 0; c < CC; c++) {
        float xv = xrow[c];
        const float* wp = W1T + (size_t)(HH + c) * 256 + og * 16;
        #pragma unroll
        for (int j4 = 0; j4 < 4; j4++) {
          float4 w4 = *(const float4*)(wp + j4 * 4);
          acc[j4 * 4 + 0] = fmaf(w4.x, xv, acc[j4 * 4 + 0]);
          acc[j4 * 4 + 1] = fmaf(w4.y, xv, acc[j4 * 4 + 1]);
          acc[j4 * 4 + 2] = fmaf(w4.z, xv, acc[j4 * 4 + 2]);
          acc[j4 * 4 + 3] = fmaf(w4.w, xv, acc[j4 * 4 + 3]);
        }
      }
      #pragma unroll
      for (int d = 0; d < 3; d++) {
        float xv = dirs[kk][d];
        const float* wp = W1T + (size_t)(HH + CC + d) * 256 + og * 16;
        #pragma unroll
        for (int j4 = 0; j4 < 4; j4++) {
          float4 w4 = *(const float4*)(wp + j4 * 4);
          acc[j4 * 4 + 0] = fmaf(w4.x, xv, acc[j4 * 4 + 0]);
          acc[j4 * 4 + 1] = fmaf(w4.y, xv, acc[j4 * 4 + 1]);
          acc[j4 * 4 + 2] = fmaf(w4.z, xv, acc[j4 * 4 + 2]);
          acc[j4 * 4 + 3] = fmaf(w4.w, xv, acc[j4 * 4 + 3]);
        }
      }
      #pragma unroll
      for (int j = 0; j < 16; j++) {
        int o = og * 16 + j;
        y1[kk * LDSS + o] = lrelu(acc[j] + b1[o]);
      }
    }
    __syncthreads();

    mlp_layer256(y1, W2T, b2, y2, kk, og);   // layer 2
    __syncthreads();
    mlp_layer256(y2, W3T, b3, g2t, kk, og);  // layer 3 (reuse g2t as y3)
    __syncthreads();

    // max-pool over this k-tile
    {
      float m = pooled[t];
      #pragma unroll 4
      for (int k2 = 0; k2 < 16; k2++) m = fmaxf(m, g2t[k2 * LDSS + t]);
      pooled[t] = m;
    }
    __syncthreads();
  }

  // mlp2 layer 1 (no bias)
  {
    float acc = 0.f;
    #pragma unroll 4
    for (int c = 0; c < 256; c++) acc += W4T[(size_t)c * 256 + t] * pooled[c];
    z1[t] = lrelu(acc);
  }
  __syncthreads();
  // mlp2 layer 2 (no bias)
  {
    float acc = 0.f;
    #pragma unroll 4
    for (int c = 0; c < 256; c++) acc += W5T[(size_t)c * 256 + t] * z1[c];
    z2[t] = lrelu(acc);
  }
  __syncthreads();
  // regress: 3 outputs
  if (t < 3) {
    float acc = regb[t];
    for (int c = 0; c < 256; c++) acc += regw[t * 256 + c] * z2[c];
    out[((size_t)b * 3 + t) * N1 + n] = acc;
  }
}

extern "C" void kernel_launch(void* const* d_in, const int* in_sizes, int n_in,
                              void* d_out, int out_size, void* d_ws, size_t ws_size,
                              hipStream_t stream) {
  const float* xyz1    = (const float*)d_in[0];
  const float* xyz2    = (const float*)d_in[1];
  const float* points1 = (const float*)d_in[2];
  const float* points2 = (const float*)d_in[3];
  const float* bf_w1 = (const float*)d_in[4],  *bf_b1 = (const float*)d_in[5];
  const float* bf_g1 = (const float*)d_in[6],  *bf_e1 = (const float*)d_in[7];
  const float* bf_w2 = (const float*)d_in[8],  *bf_b2 = (const float*)d_in[9];
  const float* bf_g2 = (const float*)d_in[10], *bf_e2 = (const float*)d_in[11];
  const float* bf_w3 = (const float*)d_in[12], *bf_b3 = (const float*)d_in[13];
  const float* bf_g3 = (const float*)d_in[14], *bf_e3 = (const float*)d_in[15];
  const float* mlp_w1 = (const float*)d_in[16], *mlp_b1 = (const float*)d_in[17];
  const float* mlp_w2 = (const float*)d_in[18], *mlp_b2 = (const float*)d_in[19];
  const float* mlp_w3 = (const float*)d_in[20], *mlp_b3 = (const float*)d_in[21];
  const float* mlp2_w1 = (const float*)d_in[22], *mlp2_w2 = (const float*)d_in[23];
  const float* reg_w = (const float*)d_in[24], *reg_b = (const float*)d_in[25];

  float* ws   = (float*)d_ws;
  float* p1   = ws + OFF_P1;
  int*   knn  = (int*)(ws + OFF_KNN);
  float* W1T  = ws + OFF_W1T;
  float* W2T  = ws + OFF_W2T;
  float* W3T  = ws + OFF_W3T;
  float* W4T  = ws + OFF_W4T;
  float* W5T  = ws + OFF_W5T;

  float* out = (float*)d_out;
  int rows = BB * N1;  // 2688

  k_transpose<<<1411, 256, 0, stream>>>(mlp_w1, mlp_w2, mlp_w3, mlp2_w1, mlp2_w2, ws);
  k_biasfold<<<rows, 128, 0, stream>>>(points1,
      bf_w1, bf_b1, bf_g1, bf_e1,
      bf_w2, bf_b2, bf_g2, bf_e2,
      bf_w3, bf_b3, bf_g3, bf_e3, p1);
  k_knn<<<rows, 256, 0, stream>>>(xyz1, xyz2, knn);
  k_fused<<<rows, 256, 0, stream>>>(xyz1, xyz2, points2, p1, knn,
      W1T, mlp_b1, W2T, mlp_b2, W3T, mlp_b3, W4T, W5T, reg_w, reg_b, out);
}

// Round 2
// 1132.807 us; speedup vs baseline: 7.0247x; 7.0247x over previous
//
#include <hip/hip_runtime.h>
#include <float.h>

#define BB 128
#define N1 21
#define N2 4096
#define CC 256   // C (points2 channels)
#define LCH 256  // LC
#define HH 128   // H
#define KNN 64
#define KP 420   // LDS X row stride (in fp16 elems): K1pad=416 +4; bank-friendly

typedef _Float16 f16;
typedef f16 f16x4 __attribute__((ext_vector_type(4)));
typedef f16 f16x8 __attribute__((ext_vector_type(8)));
typedef float f32x4 __attribute__((ext_vector_type(4)));

// ---- workspace layout (float units) ----
static const size_t OFF_P1  = 0;                                   // [2688][128] f32
static const size_t OFF_KNN = OFF_P1  + (size_t)BB * N1 * HH;      // [2688][64] int
static const size_t OFF_W4T = OFF_KNN + (size_t)BB * N1 * KNN;     // [256][256] f32
static const size_t OFF_W5T = OFF_W4T + 65536;                     // [256][256] f32
static const size_t OFF_P1H = OFF_W5T + 65536;                     // pack1 hi: 106496 f16 = 53248 f32
static const size_t OFF_P1L = OFF_P1H + 53248;
static const size_t OFF_P2H = OFF_P1L + 53248;                     // pack2 hi: 65536 f16 = 32768 f32
static const size_t OFF_P2L = OFF_P2H + 32768;
static const size_t OFF_P3H = OFF_P2L + 32768;
static const size_t OFF_P3L = OFF_P3H + 32768;

__device__ __forceinline__ float lrelu(float x) { return x > 0.f ? x : 0.1f * x; }

// fragment k-mapping: kappa(lane, j) = 4*(lane>>4) + (j&3) + 16*(j>>2)
// (used consistently for A and B packing -> any k-permutation cancels in the dot product)

// ---------------- kernel 0: weight pack/split ----------------
__device__ __forceinline__ void pack_one(int e, const float* __restrict__ w, int K,
                                         f16* __restrict__ hi, f16* __restrict__ lo) {
  int j = e & 7, lane = (e >> 3) & 63, ntg = (e >> 9) & 15, ks = e >> 13;
  int n = ntg * 16 + (lane & 15);
  int k = ks * 32 + 4 * (lane >> 4) + (j & 3) + 16 * (j >> 2);
  float v = (k < K) ? w[(size_t)n * K + k] : 0.f;
  f16 h = (f16)v;
  f16 l = (f16)(v - (float)h);
  hi[e] = h; lo[e] = l;
}

__global__ __launch_bounds__(256) void k_pack(
    const float* __restrict__ w1, const float* __restrict__ w2,
    const float* __restrict__ w3, const float* __restrict__ w4,
    const float* __restrict__ w5, float* __restrict__ ws) {
  int t = blockIdx.x * 256 + threadIdx.x;
  if (t < 131072) {   // W4T / W5T fp32 transpose for the tail
    int m = t >> 16, v = t & 65535;
    int c = v >> 8, o = v & 255;
    const float* src = m ? w5 : w4;
    float* dst = ws + (m ? OFF_W5T : OFF_W4T);
    dst[v] = src[o * 256 + c];
    return;
  }
  int u = t - 131072;
  if (u < 106496) { pack_one(u, w1, 387, (f16*)(ws + OFF_P1H), (f16*)(ws + OFF_P1L)); return; }
  u -= 106496;
  if (u < 65536)  { pack_one(u, w2, 256, (f16*)(ws + OFF_P2H), (f16*)(ws + OFF_P2L)); return; }
  u -= 65536;
  if (u < 65536)  { pack_one(u, w3, 256, (f16*)(ws + OFF_P3H), (f16*)(ws + OFF_P3L)); return; }
}

// ---------------- kernel 1: biasfold -> p1 (unchanged, passing) ----------------
__global__ __launch_bounds__(128) void k_biasfold(
    const float* __restrict__ points1,
    const float* __restrict__ w1, const float* __restrict__ bb1,
    const float* __restrict__ g1, const float* __restrict__ be1,
    const float* __restrict__ w2, const float* __restrict__ bb2,
    const float* __restrict__ g2, const float* __restrict__ be2,
    const float* __restrict__ w3, const float* __restrict__ bb3,
    const float* __restrict__ g3, const float* __restrict__ be3,
    float* __restrict__ p1out) {
  int blk = blockIdx.x;
  int b = blk / N1, n = blk % N1;
  int t = threadIdx.x;
  __shared__ float x0[LCH], x1s[HH], x2s[HH];
  const float bnS = 1.0f / sqrtf(1.0f + 1e-5f);

  x0[t]       = points1[((size_t)b * LCH + t) * N1 + n];
  x0[t + 128] = points1[((size_t)b * LCH + t + 128) * N1 + n];
  __syncthreads();
  {
    float acc = 0.f;
    const float* wr = w1 + (size_t)t * LCH;
    #pragma unroll 4
    for (int c = 0; c < LCH; c++) acc += wr[c] * x0[c];
    acc += bb1[t * N1 + n];
    acc = acc * (g1[t] * bnS) + be1[t];
    x1s[t] = lrelu(acc);
  }
  __syncthreads();
  {
    float acc = 0.f;
    const float* wr = w2 + (size_t)t * HH;
    #pragma unroll 4
    for (int c = 0; c < HH; c++) acc += wr[c] * x1s[c];
    acc += bb2[t * N1 + n];
    acc = acc * (g2[t] * bnS) + be2[t];
    x2s[t] = lrelu(acc);
  }
  __syncthreads();
  {
    float acc = 0.f;
    const float* wr = w3 + (size_t)t * HH;
    #pragma unroll 4
    for (int c = 0; c < HH; c++) acc += wr[c] * x2s[c];
    acc += bb3[t * N1 + n];
    acc = acc * (g3[t] * bnS) + be3[t];
    p1out[(size_t)blk * HH + t] = lrelu(acc);
  }
}

// ---------------- kernel 2: kNN (unchanged, passing) ----------------
__global__ __launch_bounds__(256) void k_knn(
    const float* __restrict__ xyz1, const float* __restrict__ xyz2,
    int* __restrict__ knn) {
  int blk = blockIdx.x;
  int b = blk / N1, n = blk % N1;
  int t = threadIdx.x;
  __shared__ float dist[N2];
  __shared__ float wvv[4];
  __shared__ int wii[4];

  float ax = xyz1[((size_t)b * 3 + 0) * N1 + n];
  float ay = xyz1[((size_t)b * 3 + 1) * N1 + n];
  float az = xyz1[((size_t)b * 3 + 2) * N1 + n];
  float xx1 = ax * ax + ay * ay + az * az;
  const float* X = xyz2 + (size_t)b * 3 * N2;

  for (int i = 0; i < 16; i++) {
    int j = t + i * 256;
    float px = X[j], py = X[N2 + j], pz = X[2 * N2 + j];
    float xx2 = px * px + py * py + pz * pz;
    float dot = ax * px + ay * py + az * pz;
    dist[j] = (xx1 + xx2) - 2.0f * dot;
  }
  __syncthreads();

  int* out = knn + (size_t)blk * KNN;
  for (int it = 0; it < KNN; it++) {
    float best = FLT_MAX;
    int bi = N2;
    for (int i = 0; i < 16; i++) {
      int j = t + i * 256;
      float v = dist[j];
      if (v < best) { best = v; bi = j; }
    }
    for (int off = 32; off; off >>= 1) {
      float ov = __shfl_down(best, off);
      int oi = __shfl_down(bi, off);
      if (ov < best || (ov == best && oi < bi)) { best = ov; bi = oi; }
    }
    int w = t >> 6;
    if ((t & 63) == 0) { wvv[w] = best; wii[w] = bi; }
    __syncthreads();
    if (t == 0) {
      float bv = wvv[0]; int bj = wii[0];
      for (int q = 1; q < 4; q++)
        if (wvv[q] < bv || (wvv[q] == bv && wii[q] < bj)) { bv = wvv[q]; bj = wii[q]; }
      out[it] = bj;
      dist[bj] = FLT_MAX;
    }
    __syncthreads();
  }
}

// ---------------- MFMA layer: M=64 rows x N=64 cols per wave, split-fp16 ----------------
__device__ __forceinline__ void run_layer(
    const f16* __restrict__ BH, const f16* __restrict__ BL, int KS,
    const f16* Xh, const f16* Xl,
    int w, int lane, int r16, int g, f32x4 acc[4][4]) {
  for (int ks = 0; ks < KS; ks++) {
    f16x8 Bh[4], Bl[4];
    #pragma unroll
    for (int nt = 0; nt < 4; nt++) {
      size_t fi = ((size_t)((ks * 16 + w * 4 + nt) * 64 + lane)) * 8;
      Bh[nt] = *(const f16x8*)(BH + fi);
      Bl[nt] = *(const f16x8*)(BL + fi);
    }
    f16x8 Ah[4], Al[4];
    int k0 = ks * 32 + 4 * g;
    #pragma unroll
    for (int mt = 0; mt < 4; mt++) {
      int base = (mt * 16 + r16) * KP + k0;
      f16x4 h0 = *(const f16x4*)(Xh + base);
      f16x4 h1 = *(const f16x4*)(Xh + base + 16);
      f16x4 l0 = *(const f16x4*)(Xl + base);
      f16x4 l1 = *(const f16x4*)(Xl + base + 16);
      Ah[mt] = __builtin_shufflevector(h0, h1, 0, 1, 2, 3, 4, 5, 6, 7);
      Al[mt] = __builtin_shufflevector(l0, l1, 0, 1, 2, 3, 4, 5, 6, 7);
    }
    #pragma unroll
    for (int mt = 0; mt < 4; mt++)
      #pragma unroll
      for (int nt = 0; nt < 4; nt++) {
        acc[mt][nt] = __builtin_amdgcn_mfma_f32_16x16x32_f16(Ah[mt], Bh[nt], acc[mt][nt], 0, 0, 0);
        acc[mt][nt] = __builtin_amdgcn_mfma_f32_16x16x32_f16(Ah[mt], Bl[nt], acc[mt][nt], 0, 0, 0);
        acc[mt][nt] = __builtin_amdgcn_mfma_f32_16x16x32_f16(Al[mt], Bh[nt], acc[mt][nt], 0, 0, 0);
      }
  }
}

// ---------------- kernel 3: fused gather + MFMA MLP + maxpool + mlp2 + regress ----------------
__global__ __launch_bounds__(256, 1) void k_fused2(
    const float* __restrict__ xyz1, const float* __restrict__ xyz2,
    const float* __restrict__ points2,
    const float* __restrict__ p1ws, const int* __restrict__ knn,
    const f16* __restrict__ P1H, const f16* __restrict__ P1L,
    const f16* __restrict__ P2H, const f16* __restrict__ P2L,
    const f16* __restrict__ P3H, const f16* __restrict__ P3L,
    const float* __restrict__ b1, const float* __restrict__ b2,
    const float* __restrict__ b3,
    const float* __restrict__ W4T, const float* __restrict__ W5T,
    const float* __restrict__ regw, const float* __restrict__ regb,
    float* __restrict__ out) {
  int bid = blockIdx.x;
  // XCD-locality swizzle: all 21 n1-blocks of a batch b land on one XCD (bid%8 heuristic)
  int xcd = bid & 7, slot = bid >> 3;
  int b = xcd * 16 + slot / 21;
  int n1 = slot % 21;
  int row = b * N1 + n1;

  int t = threadIdx.x;
  int lane = t & 63, w = t >> 6;
  int r16 = lane & 15, g = lane >> 4;

  __shared__ f16 Xhi[64 * KP];
  __shared__ f16 Xlo[64 * KP];
  __shared__ float p1row[HH];
  __shared__ int idxs[KNN];
  __shared__ float x1p[3];
  __shared__ float pooled[256];
  __shared__ float z1[256], z2[256];

  if (t < KNN) idxs[t] = knn[(size_t)row * KNN + t];
  if (t < HH) p1row[t] = p1ws[(size_t)row * HH + t];
  if (t < 3) x1p[t] = xyz1[((size_t)b * 3 + t) * N1 + n1];
  __syncthreads();

  // ---- stage layer-1 X = [p1(128) | g2(256) | dir(3) | 0-pad] as fp16 hi/lo ----
  for (int i = t; i < 64 * 128; i += 256) {   // p1 part (same for all rows)
    int r = i >> 7, c = i & 127;
    float v = p1row[c];
    f16 h = (f16)v;
    Xhi[r * KP + c] = h;
    Xlo[r * KP + c] = (f16)(v - (float)h);
  }
  int myid = idxs[lane];
  const float* p2b = points2 + (size_t)b * CC * N2;
  for (int i = 0; i < 64; i++) {              // g2 gather: lane=row, wave covers 64 channels
    int c = w * 64 + i;
    float v = p2b[(size_t)c * N2 + myid];
    f16 h = (f16)v;
    Xhi[lane * KP + 128 + c] = h;
    Xlo[lane * KP + 128 + c] = (f16)(v - (float)h);
  }
  if (t < 64) {                               // dir + zero pad
    const float* x2b = xyz2 + (size_t)b * 3 * N2;
    #pragma unroll
    for (int d = 0; d < 3; d++) {
      float v = x2b[(size_t)d * N2 + myid] - x1p[d];
      f16 h = (f16)v;
      Xhi[t * KP + 384 + d] = h;
      Xlo[t * KP + 384 + d] = (f16)(v - (float)h);
    }
    for (int k = 387; k < 416; k++) { Xhi[t * KP + k] = (f16)0; Xlo[t * KP + k] = (f16)0; }
  }

  float bv1[4], bv2[4], bv3[4];
  #pragma unroll
  for (int nt = 0; nt < 4; nt++) {
    int n = w * 64 + nt * 16 + r16;
    bv1[nt] = b1[n]; bv2[nt] = b2[n]; bv3[nt] = b3[n];
  }
  __syncthreads();

  f32x4 acc[4][4];

  // ---- layer 1: K=416 (13 k-steps) ----
  #pragma unroll
  for (int mt = 0; mt < 4; mt++)
    #pragma unroll
    for (int nt = 0; nt < 4; nt++) acc[mt][nt] = (f32x4){0.f, 0.f, 0.f, 0.f};
  run_layer(P1H, P1L, 13, Xhi, Xlo, w, lane, r16, g, acc);
  __syncthreads();  // everyone done reading X
  #pragma unroll
  for (int mt = 0; mt < 4; mt++)
    #pragma unroll
    for (int nt = 0; nt < 4; nt++) {
      int nl = w * 64 + nt * 16 + r16;
      #pragma unroll
      for (int j = 0; j < 4; j++) {
        int m = mt * 16 + 4 * g + j;
        float y = lrelu(acc[mt][nt][j] + bv1[nt]);
        f16 h = (f16)y;
        Xhi[m * KP + nl] = h;
        Xlo[m * KP + nl] = (f16)(y - (float)h);
      }
    }
  __syncthreads();

  // ---- layer 2: K=256 (8 k-steps) ----
  #pragma unroll
  for (int mt = 0; mt < 4; mt++)
    #pragma unroll
    for (int nt = 0; nt < 4; nt++) acc[mt][nt] = (f32x4){0.f, 0.f, 0.f, 0.f};
  run_layer(P2H, P2L, 8, Xhi, Xlo, w, lane, r16, g, acc);
  __syncthreads();
  #pragma unroll
  for (int mt = 0; mt < 4; mt++)
    #pragma unroll
    for (int nt = 0; nt < 4; nt++) {
      int nl = w * 64 + nt * 16 + r16;
      #pragma unroll
      for (int j = 0; j < 4; j++) {
        int m = mt * 16 + 4 * g + j;
        float y = lrelu(acc[mt][nt][j] + bv2[nt]);
        f16 h = (f16)y;
        Xhi[m * KP + nl] = h;
        Xlo[m * KP + nl] = (f16)(y - (float)h);
      }
    }
  __syncthreads();

  // ---- layer 3: K=256, maxpool over the 64 rows straight from accumulators ----
  #pragma unroll
  for (int mt = 0; mt < 4; mt++)
    #pragma unroll
    for (int nt = 0; nt < 4; nt++) acc[mt][nt] = (f32x4){0.f, 0.f, 0.f, 0.f};
  run_layer(P3H, P3L, 8, Xhi, Xlo, w, lane, r16, g, acc);
  #pragma unroll
  for (int nt = 0; nt < 4; nt++) {
    float m = -FLT_MAX;
    #pragma unroll
    for (int mt = 0; mt < 4; mt++)
      #pragma unroll
      for (int j = 0; j < 4; j++) m = fmaxf(m, acc[mt][nt][j]);
    m = fmaxf(m, __shfl_xor(m, 16));
    m = fmaxf(m, __shfl_xor(m, 32));
    m = lrelu(m + bv3[nt]);          // lrelu/bias commute with max (monotone, const per n)
    if (g == 0) pooled[w * 64 + nt * 16 + r16] = m;
  }
  __syncthreads();

  // ---- mlp2 (no bias) + regress, fp32 VALU ----
  {
    float a = 0.f;
    #pragma unroll 4
    for (int c = 0; c < 256; c++) a += W4T[(size_t)c * 256 + t] * pooled[c];
    z1[t] = lrelu(a);
  }
  __syncthreads();
  {
    float a = 0.f;
    #pragma unroll 4
    for (int c = 0; c < 256; c++) a += W5T[(size_t)c * 256 + t] * z1[c];
    z2[t] = lrelu(a);
  }
  __syncthreads();
  if (t < 192) {
    int o = t >> 6;
    float a = 0.f;
    #pragma unroll
    for (int i = 0; i < 4; i++) {
      int c = (t & 63) + 64 * i;
      a += regw[o * 256 + c] * z2[c];
    }
    #pragma unroll
    for (int off = 32; off; off >>= 1) a += __shfl_xor(a, off);
    if ((t & 63) == 0) out[((size_t)b * 3 + o) * N1 + n1] = a + regb[o];
  }
}

extern "C" void kernel_launch(void* const* d_in, const int* in_sizes, int n_in,
                              void* d_out, int out_size, void* d_ws, size_t ws_size,
                              hipStream_t stream) {
  const float* xyz1    = (const float*)d_in[0];
  const float* xyz2    = (const float*)d_in[1];
  const float* points1 = (const float*)d_in[2];
  const float* points2 = (const float*)d_in[3];
  const float* bf_w1 = (const float*)d_in[4],  *bf_b1 = (const float*)d_in[5];
  const float* bf_g1 = (const float*)d_in[6],  *bf_e1 = (const float*)d_in[7];
  const float* bf_w2 = (const float*)d_in[8],  *bf_b2 = (const float*)d_in[9];
  const float* bf_g2 = (const float*)d_in[10], *bf_e2 = (const float*)d_in[11];
  const float* bf_w3 = (const float*)d_in[12], *bf_b3 = (const float*)d_in[13];
  const float* bf_g3 = (const float*)d_in[14], *bf_e3 = (const float*)d_in[15];
  const float* mlp_w1 = (const float*)d_in[16], *mlp_b1 = (const float*)d_in[17];
  const float* mlp_w2 = (const float*)d_in[18], *mlp_b2 = (const float*)d_in[19];
  const float* mlp_w3 = (const float*)d_in[20], *mlp_b3 = (const float*)d_in[21];
  const float* mlp2_w1 = (const float*)d_in[22], *mlp2_w2 = (const float*)d_in[23];
  const float* reg_w = (const float*)d_in[24], *reg_b = (const float*)d_in[25];

  float* ws  = (float*)d_ws;
  float* p1  = ws + OFF_P1;
  int*   knn = (int*)(ws + OFF_KNN);

  float* out = (float*)d_out;
  int rows = BB * N1;  // 2688

  k_pack<<<1440, 256, 0, stream>>>(mlp_w1, mlp_w2, mlp_w3, mlp2_w1, mlp2_w2, ws);
  k_biasfold<<<rows, 128, 0, stream>>>(points1,
      bf_w1, bf_b1, bf_g1, bf_e1,
      bf_w2, bf_b2, bf_g2, bf_e2,
      bf_w3, bf_b3, bf_g3, bf_e3, p1);
  k_knn<<<rows, 256, 0, stream>>>(xyz1, xyz2, knn);
  k_fused2<<<rows, 256, 0, stream>>>(xyz1, xyz2, points2, p1, knn,
      (const f16*)(ws + OFF_P1H), (const f16*)(ws + OFF_P1L),
      (const f16*)(ws + OFF_P2H), (const f16*)(ws + OFF_P2L),
      (const f16*)(ws + OFF_P3H), (const f16*)(ws + OFF_P3L),
      mlp_b1, mlp_b2, mlp_b3,
      ws + OFF_W4T, ws + OFF_W5T, reg_w, reg_b, out);
}